// Round 4
// baseline (156.400 us; speedup 1.0000x reference)
//
#include <hip/hip_runtime.h>
#include <hip/hip_bf16.h>

typedef __hip_bfloat16 bf16;
typedef short bf16x8 __attribute__((ext_vector_type(8)));
typedef float f32x4 __attribute__((ext_vector_type(4)));

#define S_LEN 4096
#define NBATCH 2
#define EDIM 1024
#define DDIM 64
#define MROWS (NBATCH * S_LEN)   // 8192
#define KSPLIT 4
#define KCHUNK (EDIM / KSPLIT)   // 256

union frag_u { bf16x8 v; bf16 e[8]; };

// ---------------------------------------------------------------------------
// Pack weights (f32 in) -> split bf16 hi/lo, layout Wt[3][64][1024]
// (n-major rows, contiguous in k) so MFMA B-fragments are 16B loads.
// ---------------------------------------------------------------------------
__global__ __launch_bounds__(256) void pack_w_kernel(
    const float* __restrict__ Wq, const float* __restrict__ Wk,
    const float* __restrict__ Wv, bf16* __restrict__ Wt_hi,
    bf16* __restrict__ Wt_lo) {
  int idx = blockIdx.x * 256 + threadIdx.x;   // 0 .. 3*64*1024-1
  int mat = idx >> 16;                        // 65536 elements per matrix
  int rem = idx & 65535;
  int n = rem >> 10;
  int k = rem & 1023;
  const float* W = (mat == 0) ? Wq : ((mat == 1) ? Wk : Wv);
  float v = W[k * DDIM + n];
  bf16 h = __float2bfloat16(v);
  float lo = v - __bfloat162float(h);
  Wt_hi[idx] = h;
  Wt_lo[idx] = __float2bfloat16(lo);
}

// ---------------------------------------------------------------------------
// Fused QKV GEMM, K-split x4 for occupancy (was 2 waves/SIMD -> 8).
// Each block: 16 rows x full N=192, k-range [kp*256, kp*256+256).
// Partial sums accumulate into qkv via f32 atomicAdd (qkv is memset to 0);
// the kp==0 block adds the bias so every element gets it exactly once.
// mfma_f32_16x16x32_bf16, split-bf16 (xh*wh + xh*wl + xl*wh) for f32 accuracy.
//   A-frag: A[m][k], m = lane&15, k = (lane>>4)*8 + j
//   B-frag: B[k][n], n = lane&15, k = (lane>>4)*8 + j
//   D:      D[m][n], m = (lane>>4)*4 + reg, n = lane&15
// ---------------------------------------------------------------------------
__global__ __launch_bounds__(256) void qkv_gemm_part_kernel(
    const float* __restrict__ x, const bf16* __restrict__ Wt_hi,
    const bf16* __restrict__ Wt_lo, const float* __restrict__ bq,
    const float* __restrict__ bk, const float* __restrict__ bv,
    float* __restrict__ qkv) {
  const int lane = threadIdx.x & 63;
  const int wave = threadIdx.x >> 6;          // nt = wave*3 + t
  const int quad = lane >> 4;
  const int l16 = lane & 15;
  const int mblk = blockIdx.x >> 2;
  const int kp = blockIdx.x & 3;
  const int rowBase = mblk * 16;
  const int kbase = kp * KCHUNK;

  const float* xa = x + (size_t)(rowBase + l16) * EDIM + quad * 8 + kbase;

  f32x4 acc[3];
#pragma unroll
  for (int t = 0; t < 3; t++) acc[t] = (f32x4){0.f, 0.f, 0.f, 0.f};

  for (int k0 = 0; k0 < KCHUNK; k0 += 32) {
    float4 v0 = *(const float4*)(const void*)(xa + k0);
    float4 v1 = *(const float4*)(const void*)(xa + k0 + 4);
    float vv[8] = {v0.x, v0.y, v0.z, v0.w, v1.x, v1.y, v1.z, v1.w};
    frag_u ahi, alo;
#pragma unroll
    for (int e = 0; e < 8; e++) {
      bf16 h = __float2bfloat16(vv[e]);
      ahi.e[e] = h;
      alo.e[e] = __float2bfloat16(vv[e] - __bfloat162float(h));
    }
#pragma unroll
    for (int t = 0; t < 3; t++) {
      int nt = wave * 3 + t;
      size_t off = (size_t)(nt * 16 + l16) * EDIM + quad * 8 + kbase + k0;
      bf16x8 bh = *(const bf16x8*)(const void*)(Wt_hi + off);
      bf16x8 bl = *(const bf16x8*)(const void*)(Wt_lo + off);
      acc[t] = __builtin_amdgcn_mfma_f32_16x16x32_bf16(ahi.v, bh, acc[t], 0, 0, 0);
      acc[t] = __builtin_amdgcn_mfma_f32_16x16x32_bf16(ahi.v, bl, acc[t], 0, 0, 0);
      acc[t] = __builtin_amdgcn_mfma_f32_16x16x32_bf16(alo.v, bh, acc[t], 0, 0, 0);
    }
  }

#pragma unroll
  for (int t = 0; t < 3; t++) {
    int n = (wave * 3 + t) * 16 + l16;
    int mat = n >> 6;
    int col = n & 63;
    float bias = 0.f;
    if (kp == 0)
      bias = (mat == 0) ? bq[col] : ((mat == 1) ? bk[col] : bv[col]);
    float* dst = qkv + (size_t)mat * MROWS * DDIM +
                 (size_t)(rowBase + quad * 4) * DDIM + col;
#pragma unroll
    for (int r = 0; r < 4; r++) atomicAdd(dst + r * DDIM, acc[t][r] + bias);
  }
}

// ---------------------------------------------------------------------------
// Per-batch column sums of V (for the exp(0) background term).
// Grid = 512 blocks: b = blk>>8, 16-row chunk = blk&255. atomicAdd into Vsum.
// ---------------------------------------------------------------------------
__global__ __launch_bounds__(256) void vsum_kernel(const float* __restrict__ Vf,
                                                   float* __restrict__ Vsum) {
  int b = blockIdx.x >> 8;
  int chunk = blockIdx.x & 255;
  int col = threadIdx.x & 63;
  int rg = threadIdx.x >> 6;
  const float* base =
      Vf + ((size_t)b * S_LEN + chunk * 16 + rg * 4) * DDIM + col;
  float s = 0.f;
#pragma unroll
  for (int r = 0; r < 4; r++) s += base[r * DDIM];
  __shared__ float red[256];
  red[threadIdx.x] = s;
  __syncthreads();
  if (threadIdx.x < 64)
    atomicAdd(&Vsum[b * DDIM + col],
              red[col] + red[col + 64] + red[col + 128] + red[col + 192]);
}

// ---------------------------------------------------------------------------
// Attention: 2 queries per wave, 32 lanes each, lane owns a float2 dim-pair.
// Shuffle reduction depth 5 (masks 1..16 stay inside each 32-lane half).
// Softmax over the full row collapses to: 5 window exps + (S - nvalid)
// background exp(0-m) terms; background numerator = Vsum - sum(window V).
// ---------------------------------------------------------------------------
__global__ __launch_bounds__(256) void attn_kernel(
    const float* __restrict__ Qf, const float* __restrict__ Kf,
    const float* __restrict__ Vf, const float* __restrict__ Vsum,
    float* __restrict__ out) {
  int l = threadIdx.x & 31;                    // dim-pair index
  int qidx = blockIdx.x * 8 + (threadIdx.x >> 5);
  int b = qidx >> 12;
  int i = qidx & 4095;

  float2 q = *(const float2*)(const void*)(Qf + (size_t)qidx * DDIM + 2 * l);
  float sc[5];
  float2 vv[5];
  bool val[5];
#pragma unroll
  for (int w = 0; w < 5; w++) {
    int j = i + 2 * w - 4;               // DIL*(w - WIN/2), DIL=2
    val[w] = (j >= 0) && (j < S_LEN);
    int jj = val[w] ? j : i;
    size_t off = (size_t)(b * S_LEN + jj) * DDIM + 2 * l;
    float2 kk = *(const float2*)(const void*)(Kf + off);
    vv[w] = *(const float2*)(const void*)(Vf + off);
    float p = q.x * kk.x + q.y * kk.y;
#pragma unroll
    for (int d = 1; d < 32; d <<= 1) p += __shfl_xor(p, d, 64);
    sc[w] = p;
  }

  float mx = 0.f;  // include the background score 0 in the max
#pragma unroll
  for (int w = 0; w < 5; w++)
    if (val[w]) mx = fmaxf(mx, sc[w]);

  float denom = 0.f;
  float2 accv = {0.f, 0.f}, vsel = {0.f, 0.f};
  int nval = 0;
#pragma unroll
  for (int w = 0; w < 5; w++)
    if (val[w]) {
      float p = __expf(sc[w] - mx);
      denom += p;
      accv.x += p * vv[w].x;
      accv.y += p * vv[w].y;
      vsel.x += vv[w].x;
      vsel.y += vv[w].y;
      nval++;
    }
  float p0 = __expf(-mx);
  denom += p0 * (float)(S_LEN - nval);
  float2 vs = *(const float2*)(const void*)(Vsum + b * DDIM + 2 * l);
  accv.x += p0 * (vs.x - vsel.x);
  accv.y += p0 * (vs.y - vsel.y);

  float2 o = {accv.x / denom, accv.y / denom};
  *(float2*)(void*)(out + (size_t)qidx * DDIM + 2 * l) = o;
}

// ---------------------------------------------------------------------------
extern "C" void kernel_launch(void* const* d_in, const int* in_sizes, int n_in,
                              void* d_out, int out_size, void* d_ws,
                              size_t ws_size, hipStream_t stream) {
  const float* x = (const float*)d_in[0];
  const float* Wq = (const float*)d_in[1];
  const float* bq = (const float*)d_in[2];
  const float* Wk = (const float*)d_in[3];
  const float* bk = (const float*)d_in[4];
  const float* Wv = (const float*)d_in[5];
  const float* bv = (const float*)d_in[6];
  float* out = (float*)d_out;

  char* ws = (char*)d_ws;
  bf16* Wt_hi = (bf16*)ws;                    // 393216 B
  bf16* Wt_lo = (bf16*)(ws + 393216);         // 393216 B
  float* qkv = (float*)(ws + 786432);         // 3*8192*64*4 = 6291456 B
  float* Qf = qkv;
  float* Kf = qkv + (size_t)MROWS * DDIM;
  float* Vf = Kf + (size_t)MROWS * DDIM;
  float* Vsum = (float*)(ws + 786432 + 6291456);  // 128 floats, right after qkv
  // total workspace: ~7.08 MB

  // qkv is accumulated via atomics -> zero it (and Vsum, contiguous) first.
  hipMemsetAsync(qkv, 0, 6291456 + NBATCH * DDIM * sizeof(float), stream);
  hipLaunchKernelGGL(pack_w_kernel, dim3(768), dim3(256), 0, stream, Wq, Wk, Wv,
                     Wt_hi, Wt_lo);
  hipLaunchKernelGGL(qkv_gemm_part_kernel, dim3(2048), dim3(256), 0, stream, x,
                     Wt_hi, Wt_lo, bq, bk, bv, qkv);
  hipLaunchKernelGGL(vsum_kernel, dim3(512), dim3(256), 0, stream, Vf, Vsum);
  hipLaunchKernelGGL(attn_kernel, dim3(1024), dim3(256), 0, stream, Qf, Kf, Vf,
                     Vsum, out);
}

// Round 5
// 125.009 us; speedup vs baseline: 1.2511x; 1.2511x over previous
//
#include <hip/hip_runtime.h>
#include <hip/hip_bf16.h>

typedef __hip_bfloat16 bf16;
typedef short bf16x8 __attribute__((ext_vector_type(8)));
typedef float f32x4 __attribute__((ext_vector_type(4)));

#define S_LEN 4096
#define NBATCH 2
#define EDIM 1024
#define DDIM 64
#define MROWS (NBATCH * S_LEN)   // 8192
#define KPHASE 512               // k-range per wave-phase (2 phases)

union frag_u { bf16x8 v; bf16 e[8]; };

// f32x8 -> split bf16 hi/lo fragments (x ~= hi + lo, error ~2^-17 rel)
__device__ inline void cvt_split(const float4& a, const float4& b,
                                 bf16x8& hi, bf16x8& lo) {
  float v[8] = {a.x, a.y, a.z, a.w, b.x, b.y, b.z, b.w};
  frag_u h, l;
#pragma unroll
  for (int e = 0; e < 8; e++) {
    bf16 hh = __float2bfloat16(v[e]);
    h.e[e] = hh;
    l.e[e] = __float2bfloat16(v[e] - __bfloat162float(hh));
  }
  hi = h.v;
  lo = l.v;
}

// ---------------------------------------------------------------------------
// Pack weights (f32 in) -> split bf16 hi/lo, layout Wt[192 n-rows][1024 k]
// (n-major rows, contiguous in k) so MFMA B-fragments are 16B loads.
// Block 0 also zeroes Vsum (saves a memset dispatch).
// ---------------------------------------------------------------------------
__global__ __launch_bounds__(256) void pack_w_kernel(
    const float* __restrict__ Wq, const float* __restrict__ Wk,
    const float* __restrict__ Wv, bf16* __restrict__ Wt_hi,
    bf16* __restrict__ Wt_lo, float* __restrict__ Vsum) {
  int idx = blockIdx.x * 256 + threadIdx.x;   // 0 .. 3*64*1024-1
  if (blockIdx.x == 0 && threadIdx.x < NBATCH * DDIM) Vsum[threadIdx.x] = 0.f;
  int mat = idx >> 16;                        // 65536 elements per matrix
  int rem = idx & 65535;
  int n = rem >> 10;
  int k = rem & 1023;
  const float* W = (mat == 0) ? Wq : ((mat == 1) ? Wk : Wv);
  float v = W[k * DDIM + n];
  bf16 h = __float2bfloat16(v);
  Wt_hi[idx] = h;
  Wt_lo[idx] = __float2bfloat16(v - __bfloat162float(h));
}

// ---------------------------------------------------------------------------
// Fused QKV GEMM, software-pipelined. M=8192, K=1024, N=192.
// Grid 256 blocks x 512 threads (8 waves, 1 block/CU).
// Block tile: 32 rows x N=192. Wave (kphase, nw): kphase = wave>>2 handles
// k in [kphase*512, +512); nw = wave&3 owns n-tiles nw*3..nw*3+2.
// Per wave: 2 m-tiles x 3 n-tiles, 18 MFMA per 32-k step, explicit
// next-step prefetch registers (x float4 x4 + B bf16x8 x6 in flight).
// Epilogue: phase-1 waves dump partials to LDS, phase-0 adds + bias + store.
// mfma_f32_16x16x32_bf16 split-bf16 (xh*wh + xh*wl + xl*wh).
//   A-frag: A[m][k], m = lane&15, k = (lane>>4)*8 + j
//   B-frag: B[k][n], n = lane&15, k = (lane>>4)*8 + j
//   D:      D[m][n], m = (lane>>4)*4 + reg, n = lane&15
// ---------------------------------------------------------------------------
__global__ __launch_bounds__(512, 2) void qkv_gemm_kernel(
    const float* __restrict__ x, const bf16* __restrict__ Wt_hi,
    const bf16* __restrict__ Wt_lo, const float* __restrict__ bq,
    const float* __restrict__ bk, const float* __restrict__ bv,
    float* __restrict__ qkv) {
  __shared__ float lds_red[32 * 192];         // 24 KB
  const int tid = threadIdx.x;
  const int lane = tid & 63;
  const int wave = tid >> 6;
  const int quad = lane >> 4;
  const int l16 = lane & 15;
  const int kphase = wave >> 2;
  const int nw = wave & 3;
  const int rowBase = blockIdx.x * 32;
  const int kbase = kphase * KPHASE;

  const float* xa0 = x + (size_t)(rowBase + l16) * EDIM + quad * 8 + kbase;
  const float* xa1 = xa0 + (size_t)16 * EDIM;
  size_t boff[3];
#pragma unroll
  for (int t = 0; t < 3; t++)
    boff[t] = (size_t)((nw * 3 + t) * 16 + l16) * EDIM + quad * 8 + kbase;

  f32x4 acc[2][3];
#pragma unroll
  for (int mt = 0; mt < 2; mt++)
#pragma unroll
    for (int t = 0; t < 3; t++) acc[mt][t] = (f32x4){0.f, 0.f, 0.f, 0.f};

  // current in-flight register set
  float4 cx[4];
  bf16x8 cbh[3], cbl[3];
  cx[0] = *(const float4*)(const void*)(xa0);
  cx[1] = *(const float4*)(const void*)(xa0 + 4);
  cx[2] = *(const float4*)(const void*)(xa1);
  cx[3] = *(const float4*)(const void*)(xa1 + 4);
#pragma unroll
  for (int t = 0; t < 3; t++) {
    cbh[t] = *(const bf16x8*)(const void*)(Wt_hi + boff[t]);
    cbl[t] = *(const bf16x8*)(const void*)(Wt_lo + boff[t]);
  }

  for (int k0 = 0; k0 < KPHASE; k0 += 32) {
    const bool more = (k0 + 32) < KPHASE;
    float4 nx[4];
    bf16x8 nbh[3], nbl[3];
    if (more) {
      int k1 = k0 + 32;
      nx[0] = *(const float4*)(const void*)(xa0 + k1);
      nx[1] = *(const float4*)(const void*)(xa0 + k1 + 4);
      nx[2] = *(const float4*)(const void*)(xa1 + k1);
      nx[3] = *(const float4*)(const void*)(xa1 + k1 + 4);
#pragma unroll
      for (int t = 0; t < 3; t++) {
        nbh[t] = *(const bf16x8*)(const void*)(Wt_hi + boff[t] + k1);
        nbl[t] = *(const bf16x8*)(const void*)(Wt_lo + boff[t] + k1);
      }
    }

    bf16x8 ah0, al0, ah1, al1;
    cvt_split(cx[0], cx[1], ah0, al0);
    cvt_split(cx[2], cx[3], ah1, al1);
#pragma unroll
    for (int t = 0; t < 3; t++) {
      acc[0][t] = __builtin_amdgcn_mfma_f32_16x16x32_bf16(ah0, cbh[t], acc[0][t], 0, 0, 0);
      acc[1][t] = __builtin_amdgcn_mfma_f32_16x16x32_bf16(ah1, cbh[t], acc[1][t], 0, 0, 0);
      acc[0][t] = __builtin_amdgcn_mfma_f32_16x16x32_bf16(ah0, cbl[t], acc[0][t], 0, 0, 0);
      acc[1][t] = __builtin_amdgcn_mfma_f32_16x16x32_bf16(ah1, cbl[t], acc[1][t], 0, 0, 0);
      acc[0][t] = __builtin_amdgcn_mfma_f32_16x16x32_bf16(al0, cbh[t], acc[0][t], 0, 0, 0);
      acc[1][t] = __builtin_amdgcn_mfma_f32_16x16x32_bf16(al1, cbh[t], acc[1][t], 0, 0, 0);
    }

    if (more) {
#pragma unroll
      for (int j = 0; j < 4; j++) cx[j] = nx[j];
#pragma unroll
      for (int t = 0; t < 3; t++) {
        cbh[t] = nbh[t];
        cbl[t] = nbl[t];
      }
    }
  }

  // cross-phase reduction through LDS, then biased store (phase 0 waves).
  if (kphase == 1) {
#pragma unroll
    for (int mt = 0; mt < 2; mt++)
#pragma unroll
      for (int t = 0; t < 3; t++) {
        int n = (nw * 3 + t) * 16 + l16;
#pragma unroll
        for (int r = 0; r < 4; r++) {
          int row = mt * 16 + quad * 4 + r;
          lds_red[row * 192 + n] = acc[mt][t][r];
        }
      }
  }
  __syncthreads();
  if (kphase == 0) {
#pragma unroll
    for (int mt = 0; mt < 2; mt++)
#pragma unroll
      for (int t = 0; t < 3; t++) {
        int n = (nw * 3 + t) * 16 + l16;
        int mat = n >> 6;
        int col = n & 63;
        float bias = (mat == 0) ? bq[col] : ((mat == 1) ? bk[col] : bv[col]);
        float* dst = qkv + (size_t)mat * MROWS * DDIM +
                     (size_t)(rowBase + mt * 16 + quad * 4) * DDIM + col;
#pragma unroll
        for (int r = 0; r < 4; r++) {
          int row = mt * 16 + quad * 4 + r;
          dst[r * DDIM] = acc[mt][t][r] + lds_red[row * 192 + n] + bias;
        }
      }
  }
}

// ---------------------------------------------------------------------------
// Per-batch column sums of V (for the exp(0) background term).
// Grid = 64 blocks (32-way contention max on Vsum atomics).
// ---------------------------------------------------------------------------
__global__ __launch_bounds__(256) void vsum_kernel(const float* __restrict__ Vf,
                                                   float* __restrict__ Vsum) {
  int b = blockIdx.x >> 5;
  int chunk = blockIdx.x & 31;
  int col = threadIdx.x & 63;
  int rg = threadIdx.x >> 6;
  const float* base =
      Vf + ((size_t)b * S_LEN + chunk * 128 + rg * 32) * DDIM + col;
  float s = 0.f;
#pragma unroll
  for (int r = 0; r < 32; r++) s += base[r * DDIM];
  __shared__ float red[256];
  red[threadIdx.x] = s;
  __syncthreads();
  if (threadIdx.x < 64)
    atomicAdd(&Vsum[b * DDIM + col],
              red[col] + red[col + 64] + red[col + 128] + red[col + 192]);
}

// ---------------------------------------------------------------------------
// Attention: 2 queries per wave, 32 lanes each, lane owns a float2 dim-pair.
// Softmax over the full row collapses to: 5 window exps + (S - nvalid)
// background exp(0-m) terms; background numerator = Vsum - sum(window V).
// ---------------------------------------------------------------------------
__global__ __launch_bounds__(256) void attn_kernel(
    const float* __restrict__ Qf, const float* __restrict__ Kf,
    const float* __restrict__ Vf, const float* __restrict__ Vsum,
    float* __restrict__ out) {
  int l = threadIdx.x & 31;                    // dim-pair index
  int qidx = blockIdx.x * 8 + (threadIdx.x >> 5);
  int b = qidx >> 12;
  int i = qidx & 4095;

  float2 q = *(const float2*)(const void*)(Qf + (size_t)qidx * DDIM + 2 * l);
  float sc[5];
  float2 vv[5];
  bool val[5];
#pragma unroll
  for (int w = 0; w < 5; w++) {
    int j = i + 2 * w - 4;               // DIL*(w - WIN/2), DIL=2
    val[w] = (j >= 0) && (j < S_LEN);
    int jj = val[w] ? j : i;
    size_t off = (size_t)(b * S_LEN + jj) * DDIM + 2 * l;
    float2 kk = *(const float2*)(const void*)(Kf + off);
    vv[w] = *(const float2*)(const void*)(Vf + off);
    float p = q.x * kk.x + q.y * kk.y;
#pragma unroll
    for (int d = 1; d < 32; d <<= 1) p += __shfl_xor(p, d, 64);
    sc[w] = p;
  }

  float mx = 0.f;  // include the background score 0 in the max
#pragma unroll
  for (int w = 0; w < 5; w++)
    if (val[w]) mx = fmaxf(mx, sc[w]);

  float denom = 0.f;
  float2 accv = {0.f, 0.f}, vsel = {0.f, 0.f};
  int nval = 0;
#pragma unroll
  for (int w = 0; w < 5; w++)
    if (val[w]) {
      float p = __expf(sc[w] - mx);
      denom += p;
      accv.x += p * vv[w].x;
      accv.y += p * vv[w].y;
      vsel.x += vv[w].x;
      vsel.y += vv[w].y;
      nval++;
    }
  float p0 = __expf(-mx);
  denom += p0 * (float)(S_LEN - nval);
  float2 vs = *(const float2*)(const void*)(Vsum + b * DDIM + 2 * l);
  accv.x += p0 * (vs.x - vsel.x);
  accv.y += p0 * (vs.y - vsel.y);

  float2 o = {accv.x / denom, accv.y / denom};
  *(float2*)(void*)(out + (size_t)qidx * DDIM + 2 * l) = o;
}

// ---------------------------------------------------------------------------
extern "C" void kernel_launch(void* const* d_in, const int* in_sizes, int n_in,
                              void* d_out, int out_size, void* d_ws,
                              size_t ws_size, hipStream_t stream) {
  const float* x = (const float*)d_in[0];
  const float* Wq = (const float*)d_in[1];
  const float* bq = (const float*)d_in[2];
  const float* Wk = (const float*)d_in[3];
  const float* bk = (const float*)d_in[4];
  const float* Wv = (const float*)d_in[5];
  const float* bv = (const float*)d_in[6];
  float* out = (float*)d_out;

  char* ws = (char*)d_ws;
  bf16* Wt_hi = (bf16*)ws;                    // 393216 B
  bf16* Wt_lo = (bf16*)(ws + 393216);         // 393216 B
  float* qkv = (float*)(ws + 786432);         // 3*8192*64*4 = 6291456 B
  float* Qf = qkv;
  float* Kf = qkv + (size_t)MROWS * DDIM;
  float* Vf = Kf + (size_t)MROWS * DDIM;
  float* Vsum = (float*)(ws + 786432 + 6291456);  // 128 floats
  // total workspace: ~7.08 MB

  hipLaunchKernelGGL(pack_w_kernel, dim3(768), dim3(256), 0, stream, Wq, Wk, Wv,
                     Wt_hi, Wt_lo, Vsum);
  hipLaunchKernelGGL(qkv_gemm_kernel, dim3(256), dim3(512), 0, stream, x, Wt_hi,
                     Wt_lo, bq, bk, bv, qkv);
  hipLaunchKernelGGL(vsum_kernel, dim3(64), dim3(256), 0, stream, Vf, Vsum);
  hipLaunchKernelGGL(attn_kernel, dim3(1024), dim3(256), 0, stream, Qf, Kf, Vf,
                     Vsum, out);
}